// Round 1
// baseline (60.590 us; speedup 1.0000x reference)
//
#include <hip/hip_runtime.h>
#include <hip/hip_bf16.h>
#include <cstdint>

// Problem constants (N read from in_sizes at launch; C, D fixed by reference).
#define DIM 64
#define NC  1024

typedef __attribute__((ext_vector_type(8))) __bf16 bf16x8;
typedef __attribute__((ext_vector_type(8))) short short8;
typedef __attribute__((ext_vector_type(4))) float f32x4;

static __device__ __forceinline__ unsigned short f32_to_bf16_rne(float f) {
    unsigned int u = __builtin_bit_cast(unsigned int, f);
    unsigned int r = u + 0x7FFFu + ((u >> 16) & 1u);
    return (unsigned short)(r >> 16);
}

// ---------------------------------------------------------------------------
// Prep 1: normalized |coefs| weights -> c2w[c].y    (1 block, 1024 threads)
// ---------------------------------------------------------------------------
__global__ void coef_kernel(const float* __restrict__ coefs,
                            float2* __restrict__ c2w) {
    __shared__ float red[NC];
    const int c = threadIdx.x;
    const float a = fabsf(coefs[c]);
    red[c] = a;
    __syncthreads();
    for (int s = NC / 2; s > 0; s >>= 1) {
        if (c < s) red[c] += red[c + s];
        __syncthreads();
    }
    const float sum = red[0];
    const float w = (sum == 0.0f) ? a : a / sum;
    c2w[c].y = w;
}

// ---------------------------------------------------------------------------
// Prep 2: center norms -> c2w[c].x ; bf16(-2*centers) in MFMA B-fragment
// layout -> bfrag.   Grid: NC/64 blocks x 64 threads, one center per thread.
//
// B-fragment layout for mfma_f32_16x16x32_bf16:
//   lane supplies B[k][col] with col = lane&15, k = kb*32 + (lane>>4)*8 + j.
//   Stored as bfrag[(tile*2 + kb)*64 + lane] : short8 (16B per lane).
// ---------------------------------------------------------------------------
__global__ void center_kernel(const float* __restrict__ centers,
                              float2* __restrict__ c2w,
                              short8* __restrict__ bfrag) {
    const int c = blockIdx.x * 64 + threadIdx.x;
    const float4* row = (const float4*)(centers + (size_t)c * DIM);

    float vals[DIM];
    float c2 = 0.0f;
#pragma unroll
    for (int q = 0; q < DIM / 4; ++q) {
        float4 v = row[q];
        vals[q * 4 + 0] = v.x; vals[q * 4 + 1] = v.y;
        vals[q * 4 + 2] = v.z; vals[q * 4 + 3] = v.w;
        c2 = fmaf(v.x, v.x, c2); c2 = fmaf(v.y, v.y, c2);
        c2 = fmaf(v.z, v.z, c2); c2 = fmaf(v.w, v.w, c2);
    }
    c2w[c].x = c2;

    const int tile = c >> 4;
    const int colL = c & 15;
#pragma unroll
    for (int kb = 0; kb < 2; ++kb) {
#pragma unroll
        for (int hi = 0; hi < 4; ++hi) {
            short8 p;
#pragma unroll
            for (int j = 0; j < 8; ++j) {
                float v = -2.0f * vals[kb * 32 + hi * 8 + j];
                p[j] = (short)f32_to_bf16_rne(v);
            }
            bfrag[(tile * 2 + kb) * 64 + (hi * 16 + colL)] = p;
        }
    }
}

// ---------------------------------------------------------------------------
// Main: each wave owns 64 rows (4 groups of 16). A-frags + x2 in registers.
// Loop over 64 center-tiles (16 centers each):
//   acc init = x2[row] + c2[col];  acc += A * (-2C)  (2 MFMA)  -> acc = d^2
//   epilogue per element: max, sqrt, fma(w).
// Final: shfl-reduce over the 16 col-lanes, write mad - sum.
// ---------------------------------------------------------------------------
__global__ __launch_bounds__(256) void dist_kernel(
    const float* __restrict__ x,
    const float2* __restrict__ c2w,
    const bf16x8* __restrict__ bfrag,
    const float* __restrict__ madp,
    float* __restrict__ out)
{
    const int lane = threadIdx.x & 63;
    const int wave = threadIdx.x >> 6;
    const int lo = lane & 15;
    const int hi = lane >> 4;
    const int rowBase = blockIdx.x * 256 + wave * 64;

    bf16x8 afrag[4][2];
    float x2v[4][4];

    // Prologue: load A rows, convert to bf16 fragments, compute x2 per row.
#pragma unroll
    for (int g = 0; g < 4; ++g) {
        const int row = rowBase + g * 16 + lo;
        const float* rp = x + (size_t)row * DIM + hi * 8;
        float s2 = 0.0f;
#pragma unroll
        for (int kb = 0; kb < 2; ++kb) {
            float4 v0 = *(const float4*)(rp + kb * 32);
            float4 v1 = *(const float4*)(rp + kb * 32 + 4);
            float vv[8] = {v0.x, v0.y, v0.z, v0.w, v1.x, v1.y, v1.z, v1.w};
            short8 p;
#pragma unroll
            for (int j = 0; j < 8; ++j) {
                s2 = fmaf(vv[j], vv[j], s2);
                p[j] = (short)f32_to_bf16_rne(vv[j]);
            }
            afrag[g][kb] = __builtin_bit_cast(bf16x8, p);
        }
        // lane holds 16 of row's 64 values; combine the 4 hi-groups.
        s2 += __shfl_xor(s2, 16, 64);
        s2 += __shfl_xor(s2, 32, 64);
        // s2 = ||x_row||^2 for row (g, lo). Redistribute to accumulator layout
        // (acc element b corresponds to row g*16 + hi*4 + b).
#pragma unroll
        for (int b = 0; b < 4; ++b)
            x2v[g][b] = __shfl(s2, hi * 4 + b, 64);
    }

    float sum[4][4];
#pragma unroll
    for (int g = 0; g < 4; ++g)
#pragma unroll
        for (int b = 0; b < 4; ++b) sum[g][b] = 0.0f;

    // Main loop over 64 tiles of 16 centers.
    for (int t = 0; t < NC / 16; ++t) {
        const float2 cw = c2w[t * 16 + lo];
        const bf16x8 b0 = bfrag[t * 128 + lane];
        const bf16x8 b1 = bfrag[t * 128 + 64 + lane];
#pragma unroll
        for (int g = 0; g < 4; ++g) {
            f32x4 acc;
#pragma unroll
            for (int b = 0; b < 4; ++b) acc[b] = x2v[g][b] + cw.x;
            acc = __builtin_amdgcn_mfma_f32_16x16x32_bf16(afrag[g][0], b0, acc, 0, 0, 0);
            acc = __builtin_amdgcn_mfma_f32_16x16x32_bf16(afrag[g][1], b1, acc, 0, 0, 0);
#pragma unroll
            for (int b = 0; b < 4; ++b) {
                float d2 = fmaxf(acc[b], 0.0f);
                float d  = __builtin_amdgcn_sqrtf(d2);
                sum[g][b] = fmaf(cw.y, d, sum[g][b]);
            }
        }
    }

    const float mad = madp[0];
    // Reduce over the 16 col-lanes (same hi group), then write.
#pragma unroll
    for (int g = 0; g < 4; ++g) {
#pragma unroll
        for (int b = 0; b < 4; ++b) {
            float v = sum[g][b];
            v += __shfl_xor(v, 1, 64);
            v += __shfl_xor(v, 2, 64);
            v += __shfl_xor(v, 4, 64);
            v += __shfl_xor(v, 8, 64);
            if (lo == 0)
                out[rowBase + g * 16 + hi * 4 + b] = mad - v;
        }
    }
}

extern "C" void kernel_launch(void* const* d_in, const int* in_sizes, int n_in,
                              void* d_out, int out_size, void* d_ws, size_t ws_size,
                              hipStream_t stream) {
    const float* x       = (const float*)d_in[0];
    const float* centers = (const float*)d_in[1];
    const float* coefs   = (const float*)d_in[2];
    const float* mad     = (const float*)d_in[3];
    float* out = (float*)d_out;

    float2* c2w  = (float2*)d_ws;
    short8* bfrag = (short8*)((char*)d_ws + NC * sizeof(float2));

    const int N = in_sizes[0] / DIM;

    coef_kernel<<<1, NC, 0, stream>>>(coefs, c2w);
    center_kernel<<<NC / 64, 64, 0, stream>>>(centers, c2w, bfrag);
    dist_kernel<<<N / 256, 256, 0, stream>>>(x, c2w, (const bf16x8*)bfrag, mad, out);
}

// Round 2
// 59.623 us; speedup vs baseline: 1.0162x; 1.0162x over previous
//
#include <hip/hip_runtime.h>
#include <hip/hip_bf16.h>
#include <cstdint>

// Problem constants (N read from in_sizes at launch; C, D fixed by reference).
#define DIM 64
#define NC  1024

typedef __attribute__((ext_vector_type(8))) __bf16 bf16x8;
typedef __attribute__((ext_vector_type(8))) short short8;
typedef __attribute__((ext_vector_type(4))) float f32x4;

static __device__ __forceinline__ unsigned short f32_to_bf16_rne(float f) {
    unsigned int u = __builtin_bit_cast(unsigned int, f);
    unsigned int r = u + 0x7FFFu + ((u >> 16) & 1u);
    return (unsigned short)(r >> 16);
}

// ---------------------------------------------------------------------------
// Prep 1: normalized |coefs| weights -> c2w[c].y    (1 block, 1024 threads)
// ---------------------------------------------------------------------------
__global__ void coef_kernel(const float* __restrict__ coefs,
                            float2* __restrict__ c2w) {
    __shared__ float red[NC];
    const int c = threadIdx.x;
    const float a = fabsf(coefs[c]);
    red[c] = a;
    __syncthreads();
    for (int s = NC / 2; s > 0; s >>= 1) {
        if (c < s) red[c] += red[c + s];
        __syncthreads();
    }
    const float sum = red[0];
    const float w = (sum == 0.0f) ? a : a / sum;
    c2w[c].y = w;
}

// ---------------------------------------------------------------------------
// Prep 2: center norms -> c2w[c].x ; bf16(-2*centers) in MFMA B-fragment
// layout -> bfrag.   Grid: NC/64 blocks x 64 threads, one center per thread.
//
// B-fragment layout for mfma_f32_16x16x32_bf16:
//   lane supplies B[k][col] with col = lane&15, k = kb*32 + (lane>>4)*8 + j.
//   Stored as bfrag[(tile*2 + kb)*64 + lane] : short8 (16B per lane).
// ---------------------------------------------------------------------------
__global__ void center_kernel(const float* __restrict__ centers,
                              float2* __restrict__ c2w,
                              short8* __restrict__ bfrag) {
    const int c = blockIdx.x * 64 + threadIdx.x;
    const float4* row = (const float4*)(centers + (size_t)c * DIM);

    float vals[DIM];
    float c2 = 0.0f;
#pragma unroll
    for (int q = 0; q < DIM / 4; ++q) {
        float4 v = row[q];
        vals[q * 4 + 0] = v.x; vals[q * 4 + 1] = v.y;
        vals[q * 4 + 2] = v.z; vals[q * 4 + 3] = v.w;
        c2 = fmaf(v.x, v.x, c2); c2 = fmaf(v.y, v.y, c2);
        c2 = fmaf(v.z, v.z, c2); c2 = fmaf(v.w, v.w, c2);
    }
    c2w[c].x = c2;

    const int tile = c >> 4;
    const int colL = c & 15;
#pragma unroll
    for (int kb = 0; kb < 2; ++kb) {
#pragma unroll
        for (int hi = 0; hi < 4; ++hi) {
            short8 p;
#pragma unroll
            for (int j = 0; j < 8; ++j) {
                float v = -2.0f * vals[kb * 32 + hi * 8 + j];
                p[j] = (short)f32_to_bf16_rne(v);
            }
            bfrag[(tile * 2 + kb) * 64 + (hi * 16 + colL)] = p;
        }
    }
}

// ---------------------------------------------------------------------------
// Main: block = 256 threads = 4 waves = 2 wave-pairs.
//   Wave pair p (waves 2p, 2p+1) owns rows [blockBase + p*64, +64).
//   Within a pair, wave parity selects a 512-center half (C-split=2).
// Each wave: A-frags (4 groups of 16 rows) + x2 in registers; loop over its
// 32 center-tiles with a 1-deep software pipeline on the B-fragment loads.
//   acc init = x2[row] + c2[col]; acc += A * (-2C) (2 MFMA) -> acc = d^2
//   epilogue: d = sqrt(|d2|) (abs = free input modifier); sum += w*d.
// Final: shfl-reduce over 16 col-lanes, LDS-combine the two halves, write.
// ---------------------------------------------------------------------------
__global__ __launch_bounds__(256) void dist_kernel(
    const float* __restrict__ x,
    const float2* __restrict__ c2w,
    const bf16x8* __restrict__ bfrag,
    const float* __restrict__ madp,
    float* __restrict__ out)
{
    const int lane = threadIdx.x & 63;
    const int wave = threadIdx.x >> 6;
    const int lo = lane & 15;
    const int hi = lane >> 4;
    const int pairIdx = wave >> 1;     // which 64-row group of the block
    const int halfC  = wave & 1;       // which 512-center half
    const int rowBase = blockIdx.x * 128 + pairIdx * 64;

    __shared__ float part[4][64];

    bf16x8 afrag[4][2];
    float x2v[4][4];

    // Prologue: load A rows, convert to bf16 fragments, compute x2 per row.
#pragma unroll
    for (int g = 0; g < 4; ++g) {
        const int row = rowBase + g * 16 + lo;
        const float* rp = x + (size_t)row * DIM + hi * 8;
        float s2 = 0.0f;
#pragma unroll
        for (int kb = 0; kb < 2; ++kb) {
            float4 v0 = *(const float4*)(rp + kb * 32);
            float4 v1 = *(const float4*)(rp + kb * 32 + 4);
            float vv[8] = {v0.x, v0.y, v0.z, v0.w, v1.x, v1.y, v1.z, v1.w};
            short8 p;
#pragma unroll
            for (int j = 0; j < 8; ++j) {
                s2 = fmaf(vv[j], vv[j], s2);
                p[j] = (short)f32_to_bf16_rne(vv[j]);
            }
            afrag[g][kb] = __builtin_bit_cast(bf16x8, p);
        }
        // lane holds 16 of row's 64 values; combine the 4 hi-groups.
        s2 += __shfl_xor(s2, 16, 64);
        s2 += __shfl_xor(s2, 32, 64);
        // Redistribute to accumulator layout (acc elem b <-> row g*16+hi*4+b).
#pragma unroll
        for (int b = 0; b < 4; ++b)
            x2v[g][b] = __shfl(s2, hi * 4 + b, 64);
    }

    float sum[4][4];
#pragma unroll
    for (int g = 0; g < 4; ++g)
#pragma unroll
        for (int b = 0; b < 4; ++b) sum[g][b] = 0.0f;

    // Main loop: 32 tiles of 16 centers, 1-deep software pipeline on B loads.
    const int tbase = halfC * 32;
    int t = tbase;
    bf16x8 b0 = bfrag[t * 128 + lane];
    bf16x8 b1 = bfrag[t * 128 + 64 + lane];
    float2 cw = c2w[t * 16 + lo];

#pragma unroll 2
    for (int i = 0; i < 32; ++i) {
        const int tn = (i == 31) ? tbase : (t + 1);   // wrap: stay in-bounds
        bf16x8 nb0 = bfrag[tn * 128 + lane];
        bf16x8 nb1 = bfrag[tn * 128 + 64 + lane];
        float2 ncw = c2w[tn * 16 + lo];

#pragma unroll
        for (int g = 0; g < 4; ++g) {
            f32x4 acc;
#pragma unroll
            for (int b = 0; b < 4; ++b) acc[b] = x2v[g][b] + cw.x;
            acc = __builtin_amdgcn_mfma_f32_16x16x32_bf16(afrag[g][0], b0, acc, 0, 0, 0);
            acc = __builtin_amdgcn_mfma_f32_16x16x32_bf16(afrag[g][1], b1, acc, 0, 0, 0);
#pragma unroll
            for (int b = 0; b < 4; ++b) {
                float d = __builtin_amdgcn_sqrtf(fabsf(acc[b]));
                sum[g][b] = fmaf(cw.y, d, sum[g][b]);
            }
        }
        b0 = nb0; b1 = nb1; cw = ncw; t = tn;
    }

    // Reduce over the 16 col-lanes of this wave's half, park in LDS.
#pragma unroll
    for (int g = 0; g < 4; ++g) {
#pragma unroll
        for (int b = 0; b < 4; ++b) {
            float v = sum[g][b];
            v += __shfl_xor(v, 1, 64);
            v += __shfl_xor(v, 2, 64);
            v += __shfl_xor(v, 4, 64);
            v += __shfl_xor(v, 8, 64);
            if (lo == 0) part[wave][g * 16 + hi * 4 + b] = v;
        }
    }
    __syncthreads();

    // Combine the two center-halves and write 128 rows.
    const int tid = threadIdx.x;
    if (tid < 128) {
        const int p = tid >> 6;
        const int r = tid & 63;
        const float s = part[2 * p][r] + part[2 * p + 1][r];
        out[blockIdx.x * 128 + p * 64 + r] = madp[0] - s;
    }
}

extern "C" void kernel_launch(void* const* d_in, const int* in_sizes, int n_in,
                              void* d_out, int out_size, void* d_ws, size_t ws_size,
                              hipStream_t stream) {
    const float* x       = (const float*)d_in[0];
    const float* centers = (const float*)d_in[1];
    const float* coefs   = (const float*)d_in[2];
    const float* mad     = (const float*)d_in[3];
    float* out = (float*)d_out;

    float2* c2w  = (float2*)d_ws;
    short8* bfrag = (short8*)((char*)d_ws + NC * sizeof(float2));

    const int N = in_sizes[0] / DIM;

    coef_kernel<<<1, NC, 0, stream>>>(coefs, c2w);
    center_kernel<<<NC / 64, 64, 0, stream>>>(centers, c2w, bfrag);
    dist_kernel<<<N / 128, 256, 0, stream>>>(x, c2w, (const bf16x8*)bfrag, mad, out);
}

// Round 3
// 51.187 us; speedup vs baseline: 1.1837x; 1.1648x over previous
//
#include <hip/hip_runtime.h>
#include <hip/hip_bf16.h>
#include <cstdint>

// Problem constants (N read from in_sizes at launch; C, D fixed by reference).
#define DIM 64
#define NC  1024
#define PF  4   // register-pipeline depth (tiles in flight)

typedef __attribute__((ext_vector_type(8))) __bf16 bf16x8;
typedef __attribute__((ext_vector_type(8))) short short8;
typedef __attribute__((ext_vector_type(4))) float f32x4;
typedef __attribute__((ext_vector_type(4))) unsigned int uint4v;

static __device__ __forceinline__ unsigned short f32_to_bf16_rne(float f) {
    unsigned int u = __builtin_bit_cast(unsigned int, f);
    unsigned int r = u + 0x7FFFu + ((u >> 16) & 1u);
    return (unsigned short)(r >> 16);
}
static __device__ __forceinline__ float bf16_bits_to_f32(unsigned short h) {
    return __builtin_bit_cast(float, (unsigned int)h << 16);
}

// ---------------------------------------------------------------------------
// Prep 1: normalized |coefs| weights -> wc2[c].x    (1 block, 1024 threads)
// ---------------------------------------------------------------------------
__global__ void coef_kernel(const float* __restrict__ coefs,
                            float2* __restrict__ wc2) {
    __shared__ float red[NC];
    const int c = threadIdx.x;
    const float a = fabsf(coefs[c]);
    red[c] = a;
    __syncthreads();
    for (int s = NC / 2; s > 0; s >>= 1) {
        if (c < s) red[c] += red[c + s];
        __syncthreads();
    }
    const float sum = red[0];
    const float w = (sum == 0.0f) ? a : a / sum;
    wc2[c].x = w;
}

// ---------------------------------------------------------------------------
// Prep 2: per-center c2 as a bf16 (hi, residual) pair packed in wc2[c].y;
// bf16(-2*centers) in MFMA B-fragment layout -> bfrag.
// Grid: NC/64 blocks x 64 threads, one center per thread.
//
// B-fragment layout for mfma_f32_16x16x32_bf16:
//   lane supplies B[k][col] with col = lane&15, k = (lane>>4)*8 + j.
//   Stored as bfrag[(tile*2 + kb)*64 + lane] : short8 (16B per lane).
// ---------------------------------------------------------------------------
__global__ void center_kernel(const float* __restrict__ centers,
                              float2* __restrict__ wc2,
                              short8* __restrict__ bfrag) {
    const int c = blockIdx.x * 64 + threadIdx.x;
    const float4* row = (const float4*)(centers + (size_t)c * DIM);

    float vals[DIM];
    float c2 = 0.0f;
#pragma unroll
    for (int q = 0; q < DIM / 4; ++q) {
        float4 v = row[q];
        vals[q * 4 + 0] = v.x; vals[q * 4 + 1] = v.y;
        vals[q * 4 + 2] = v.z; vals[q * 4 + 3] = v.w;
        c2 = fmaf(v.x, v.x, c2); c2 = fmaf(v.y, v.y, c2);
        c2 = fmaf(v.z, v.z, c2); c2 = fmaf(v.w, v.w, c2);
    }
    // hi + residual bf16 split: k=0 slot carries hi, k=1 slot carries lo.
    const unsigned short hi = f32_to_bf16_rne(c2);
    const unsigned short lo = f32_to_bf16_rne(c2 - bf16_bits_to_f32(hi));
    const unsigned int packed = (unsigned int)hi | ((unsigned int)lo << 16);
    wc2[c].y = __builtin_bit_cast(float, packed);

    const int tile = c >> 4;
    const int colL = c & 15;
#pragma unroll
    for (int kb = 0; kb < 2; ++kb) {
#pragma unroll
        for (int h = 0; h < 4; ++h) {
            short8 p;
#pragma unroll
            for (int j = 0; j < 8; ++j) {
                float v = -2.0f * vals[kb * 32 + h * 8 + j];
                p[j] = (short)f32_to_bf16_rne(v);
            }
            bfrag[(tile * 2 + kb) * 64 + (h * 16 + colL)] = p;
        }
    }
}

// ---------------------------------------------------------------------------
// Main: block = 256 threads = 4 waves = 2 wave-pairs.
//   Wave pair p (waves 2p, 2p+1) owns rows [blockBase + p*64, +64).
//   Wave parity selects a 512-center half (C-split=2).
// Per tile t (16 centers):
//   acc = mfma(ones[1,1,0..], bc2(t), C = x2)    // acc = x2 + c2  (matrix pipe)
//   acc = mfma(A0, B0(t), acc); acc = mfma(A1, B1(t), acc)  // acc = d^2
//   epilogue: d = sqrt(|acc|); sum = fma(w, d, sum)          // 2 VALU/elem
// B-fragments + per-center scalars ride a depth-PF register pipeline
// (statically indexed circular slots).
// ---------------------------------------------------------------------------
__global__ __launch_bounds__(256) void dist_kernel(
    const float* __restrict__ x,
    const float2* __restrict__ wc2,
    const bf16x8* __restrict__ bfrag,
    const float* __restrict__ madp,
    float* __restrict__ out)
{
    const int lane = threadIdx.x & 63;
    const int wave = threadIdx.x >> 6;
    const int lo = lane & 15;
    const int hi = lane >> 4;
    const int pairIdx = wave >> 1;     // which 64-row group of the block
    const int halfC  = wave & 1;       // which 512-center half
    const int rowBase = blockIdx.x * 128 + pairIdx * 64;

    __shared__ float part[4][64];

    bf16x8 afrag[4][2];
    f32x4 x2c[4];

    // Prologue: load A rows, convert to bf16 fragments, compute x2 per row.
#pragma unroll
    for (int g = 0; g < 4; ++g) {
        const int row = rowBase + g * 16 + lo;
        const float* rp = x + (size_t)row * DIM + hi * 8;
        float s2 = 0.0f;
#pragma unroll
        for (int kb = 0; kb < 2; ++kb) {
            float4 v0 = *(const float4*)(rp + kb * 32);
            float4 v1 = *(const float4*)(rp + kb * 32 + 4);
            float vv[8] = {v0.x, v0.y, v0.z, v0.w, v1.x, v1.y, v1.z, v1.w};
            short8 p;
#pragma unroll
            for (int j = 0; j < 8; ++j) {
                s2 = fmaf(vv[j], vv[j], s2);
                p[j] = (short)f32_to_bf16_rne(vv[j]);
            }
            afrag[g][kb] = __builtin_bit_cast(bf16x8, p);
        }
        // lane holds 16 of row's 64 values; combine the 4 hi-groups.
        s2 += __shfl_xor(s2, 16, 64);
        s2 += __shfl_xor(s2, 32, 64);
        // Redistribute to accumulator layout (acc elem b <-> row g*16+hi*4+b).
#pragma unroll
        for (int b = 0; b < 4; ++b)
            x2c[g][b] = __shfl(s2, hi * 4 + b, 64);
    }

    // Constant A fragment [1,1,0,...,0] (k=0,1 live in the hi==0 lane group).
    const unsigned int ao = (hi == 0) ? 0x3F803F80u : 0u;
    const bf16x8 afones = __builtin_bit_cast(bf16x8, (uint4v){ao, 0u, 0u, 0u});

    float sum[4][4];
#pragma unroll
    for (int g = 0; g < 4; ++g)
#pragma unroll
        for (int b = 0; b < 4; ++b) sum[g][b] = 0.0f;

    const int tbase = halfC * 32;
    const bf16x8* bp = bfrag + lane;     // lane-fixed base
    const float2* wp = wc2 + lo;

    // Fill the register pipeline: slots j = tiles tbase+j.
    bf16x8 pb0[PF], pb1[PF];
    float2 pwc[PF];
#pragma unroll
    for (int j = 0; j < PF; ++j) {
        const int t = tbase + j;
        pb0[j] = bp[t * 128];
        pb1[j] = bp[t * 128 + 64];
        pwc[j] = wp[t * 16];
    }

    for (int i = 0; i < 32; i += PF) {
#pragma unroll
        for (int j = 0; j < PF; ++j) {
            const float2 wc = pwc[j];
            const float w = wc.x;
            const unsigned int packed = __builtin_bit_cast(unsigned int, wc.y);
            const bf16x8 bc2 = __builtin_bit_cast(bf16x8, (uint4v){packed, 0u, 0u, 0u});
            const bf16x8 b0 = pb0[j];
            const bf16x8 b1 = pb1[j];

            // Prefetch tile i+j+PF into slot j (wrap to tbase at the tail;
            // harmless redundant load, keeps indices in-bounds).
            {
                const int nxt = i + j + PF;
                const int tn = tbase + ((nxt < 32) ? nxt : 0);
                pb0[j] = bp[tn * 128];
                pb1[j] = bp[tn * 128 + 64];
                pwc[j] = wp[tn * 16];
            }

#pragma unroll
            for (int g = 0; g < 4; ++g) {
                f32x4 acc;
                acc = __builtin_amdgcn_mfma_f32_16x16x32_bf16(afones, bc2, x2c[g], 0, 0, 0);
                acc = __builtin_amdgcn_mfma_f32_16x16x32_bf16(afrag[g][0], b0, acc, 0, 0, 0);
                acc = __builtin_amdgcn_mfma_f32_16x16x32_bf16(afrag[g][1], b1, acc, 0, 0, 0);
#pragma unroll
                for (int b = 0; b < 4; ++b) {
                    float d = __builtin_amdgcn_sqrtf(fabsf(acc[b]));
                    sum[g][b] = fmaf(w, d, sum[g][b]);
                }
            }
        }
    }

    // Reduce over the 16 col-lanes of this wave's half, park in LDS.
#pragma unroll
    for (int g = 0; g < 4; ++g) {
#pragma unroll
        for (int b = 0; b < 4; ++b) {
            float v = sum[g][b];
            v += __shfl_xor(v, 1, 64);
            v += __shfl_xor(v, 2, 64);
            v += __shfl_xor(v, 4, 64);
            v += __shfl_xor(v, 8, 64);
            if (lo == 0) part[wave][g * 16 + hi * 4 + b] = v;
        }
    }
    __syncthreads();

    // Combine the two center-halves and write 128 rows.
    const int tid = threadIdx.x;
    if (tid < 128) {
        const int p = tid >> 6;
        const int r = tid & 63;
        const float s = part[2 * p][r] + part[2 * p + 1][r];
        out[blockIdx.x * 128 + p * 64 + r] = madp[0] - s;
    }
}

extern "C" void kernel_launch(void* const* d_in, const int* in_sizes, int n_in,
                              void* d_out, int out_size, void* d_ws, size_t ws_size,
                              hipStream_t stream) {
    const float* x       = (const float*)d_in[0];
    const float* centers = (const float*)d_in[1];
    const float* coefs   = (const float*)d_in[2];
    const float* mad     = (const float*)d_in[3];
    float* out = (float*)d_out;

    float2* wc2  = (float2*)d_ws;
    short8* bfrag = (short8*)((char*)d_ws + NC * sizeof(float2));

    const int N = in_sizes[0] / DIM;

    coef_kernel<<<1, NC, 0, stream>>>(coefs, wc2);
    center_kernel<<<NC / 64, 64, 0, stream>>>(centers, wc2, bfrag);
    dist_kernel<<<N / 128, 256, 0, stream>>>(x, wc2, (const bf16x8*)bfrag, mad, out);
}

// Round 4
// 46.288 us; speedup vs baseline: 1.3090x; 1.1058x over previous
//
#include <hip/hip_runtime.h>
#include <hip/hip_bf16.h>
#include <cstdint>

// Problem constants (N read from in_sizes at launch; C, D fixed by reference).
#define DIM 64
#define NC  1024
#define PF  2   // register-pipeline depth (tiles in flight) — trimmed to fit
                // the 128-reg budget of __launch_bounds__(256,4)

typedef __attribute__((ext_vector_type(8))) __bf16 bf16x8;
typedef __attribute__((ext_vector_type(8))) short short8;
typedef __attribute__((ext_vector_type(4))) float f32x4;
typedef __attribute__((ext_vector_type(4))) unsigned int uint4v;

static __device__ __forceinline__ unsigned short f32_to_bf16_rne(float f) {
    unsigned int u = __builtin_bit_cast(unsigned int, f);
    unsigned int r = u + 0x7FFFu + ((u >> 16) & 1u);
    return (unsigned short)(r >> 16);
}
static __device__ __forceinline__ float bf16_bits_to_f32(unsigned short h) {
    return __builtin_bit_cast(float, (unsigned int)h << 16);
}

// ---------------------------------------------------------------------------
// Prep 1: normalized |coefs| weights -> wc2[c].x    (1 block, 1024 threads)
// ---------------------------------------------------------------------------
__global__ void coef_kernel(const float* __restrict__ coefs,
                            float2* __restrict__ wc2) {
    __shared__ float red[NC];
    const int c = threadIdx.x;
    const float a = fabsf(coefs[c]);
    red[c] = a;
    __syncthreads();
    for (int s = NC / 2; s > 0; s >>= 1) {
        if (c < s) red[c] += red[c + s];
        __syncthreads();
    }
    const float sum = red[0];
    const float w = (sum == 0.0f) ? a : a / sum;
    wc2[c].x = w;
}

// ---------------------------------------------------------------------------
// Prep 2: per-center c2 as a bf16 (hi, residual) pair packed in wc2[c].y;
// bf16(-2*centers) in MFMA B-fragment layout -> bfrag.
// Grid: NC/64 blocks x 64 threads, one center per thread.
//
// B-fragment layout for mfma_f32_16x16x32_bf16:
//   lane supplies B[k][col] with col = lane&15, k = (lane>>4)*8 + j.
//   Stored as bfrag[(tile*2 + kb)*64 + lane] : short8 (16B per lane).
// ---------------------------------------------------------------------------
__global__ void center_kernel(const float* __restrict__ centers,
                              float2* __restrict__ wc2,
                              short8* __restrict__ bfrag) {
    const int c = blockIdx.x * 64 + threadIdx.x;
    const float4* row = (const float4*)(centers + (size_t)c * DIM);

    float vals[DIM];
    float c2 = 0.0f;
#pragma unroll
    for (int q = 0; q < DIM / 4; ++q) {
        float4 v = row[q];
        vals[q * 4 + 0] = v.x; vals[q * 4 + 1] = v.y;
        vals[q * 4 + 2] = v.z; vals[q * 4 + 3] = v.w;
        c2 = fmaf(v.x, v.x, c2); c2 = fmaf(v.y, v.y, c2);
        c2 = fmaf(v.z, v.z, c2); c2 = fmaf(v.w, v.w, c2);
    }
    // hi + residual bf16 split: k=0 slot carries hi, k=1 slot carries lo.
    const unsigned short hi = f32_to_bf16_rne(c2);
    const unsigned short lo = f32_to_bf16_rne(c2 - bf16_bits_to_f32(hi));
    const unsigned int packed = (unsigned int)hi | ((unsigned int)lo << 16);
    wc2[c].y = __builtin_bit_cast(float, packed);

    const int tile = c >> 4;
    const int colL = c & 15;
#pragma unroll
    for (int kb = 0; kb < 2; ++kb) {
#pragma unroll
        for (int h = 0; h < 4; ++h) {
            short8 p;
#pragma unroll
            for (int j = 0; j < 8; ++j) {
                float v = -2.0f * vals[kb * 32 + h * 8 + j];
                p[j] = (short)f32_to_bf16_rne(v);
            }
            bfrag[(tile * 2 + kb) * 64 + (h * 16 + colL)] = p;
        }
    }
}

// ---------------------------------------------------------------------------
// Main: block = 256 threads = 4 waves = 2 wave-pairs.
//   Wave pair p (waves 2p, 2p+1) owns rows [blockBase + p*64, +64).
//   Wave parity selects a 512-center half (C-split=2).
// Per tile t (16 centers):
//   acc = mfma(ones[1,1,0..], bc2(t), C = x2)    // acc = x2 + c2  (matrix pipe)
//   acc = mfma(A0, B0(t), acc); acc = mfma(A1, B1(t), acc)  // acc = d^2
//   epilogue: d = sqrt(|acc|); sum = fma(w, d, sum)          // 2 VALU/elem
// B-fragments + per-center scalars ride a depth-PF register pipeline
// (statically indexed circular slots).
// __launch_bounds__(256, 4): 4 blocks/CU = 4 waves/SIMD -> 128-reg budget
// (arch+acc combined on gfx950) so the waves actually become RESIDENT.
// ---------------------------------------------------------------------------
__global__ __launch_bounds__(256, 4) void dist_kernel(
    const float* __restrict__ x,
    const float2* __restrict__ wc2,
    const bf16x8* __restrict__ bfrag,
    const float* __restrict__ madp,
    float* __restrict__ out)
{
    const int lane = threadIdx.x & 63;
    const int wave = threadIdx.x >> 6;
    const int lo = lane & 15;
    const int hi = lane >> 4;
    const int pairIdx = wave >> 1;     // which 64-row group of the block
    const int halfC  = wave & 1;       // which 512-center half
    const int rowBase = blockIdx.x * 128 + pairIdx * 64;

    __shared__ float part[4][64];

    bf16x8 afrag[4][2];
    f32x4 x2c[4];

    // Prologue: load A rows, convert to bf16 fragments, compute x2 per row.
#pragma unroll
    for (int g = 0; g < 4; ++g) {
        const int row = rowBase + g * 16 + lo;
        const float* rp = x + (size_t)row * DIM + hi * 8;
        float s2 = 0.0f;
#pragma unroll
        for (int kb = 0; kb < 2; ++kb) {
            float4 v0 = *(const float4*)(rp + kb * 32);
            float4 v1 = *(const float4*)(rp + kb * 32 + 4);
            float vv[8] = {v0.x, v0.y, v0.z, v0.w, v1.x, v1.y, v1.z, v1.w};
            short8 p;
#pragma unroll
            for (int j = 0; j < 8; ++j) {
                s2 = fmaf(vv[j], vv[j], s2);
                p[j] = (short)f32_to_bf16_rne(vv[j]);
            }
            afrag[g][kb] = __builtin_bit_cast(bf16x8, p);
        }
        // lane holds 16 of row's 64 values; combine the 4 hi-groups.
        s2 += __shfl_xor(s2, 16, 64);
        s2 += __shfl_xor(s2, 32, 64);
        // Redistribute to accumulator layout (acc elem b <-> row g*16+hi*4+b).
#pragma unroll
        for (int b = 0; b < 4; ++b)
            x2c[g][b] = __shfl(s2, hi * 4 + b, 64);
    }

    // Constant A fragment [1,1,0,...,0] (k=0,1 live in the hi==0 lane group).
    const unsigned int ao = (hi == 0) ? 0x3F803F80u : 0u;
    const bf16x8 afones = __builtin_bit_cast(bf16x8, (uint4v){ao, 0u, 0u, 0u});

    float sum[4][4];
#pragma unroll
    for (int g = 0; g < 4; ++g)
#pragma unroll
        for (int b = 0; b < 4; ++b) sum[g][b] = 0.0f;

    const int tbase = halfC * 32;
    const bf16x8* bp = bfrag + lane;     // lane-fixed base
    const float2* wp = wc2 + lo;

    // Fill the register pipeline: slots j = tiles tbase+j.
    bf16x8 pb0[PF], pb1[PF];
    float2 pwc[PF];
#pragma unroll
    for (int j = 0; j < PF; ++j) {
        const int t = tbase + j;
        pb0[j] = bp[t * 128];
        pb1[j] = bp[t * 128 + 64];
        pwc[j] = wp[t * 16];
    }

    for (int i = 0; i < 32; i += PF) {
#pragma unroll
        for (int j = 0; j < PF; ++j) {
            const float2 wc = pwc[j];
            const float w = wc.x;
            const unsigned int packed = __builtin_bit_cast(unsigned int, wc.y);
            const bf16x8 bc2 = __builtin_bit_cast(bf16x8, (uint4v){(hi == 0) ? packed : 0u, 0u, 0u, 0u});
            const bf16x8 b0 = pb0[j];
            const bf16x8 b1 = pb1[j];

            // Prefetch tile i+j+PF into slot j (wrap to tbase at the tail;
            // harmless redundant load, keeps indices in-bounds).
            {
                const int nxt = i + j + PF;
                const int tn = tbase + ((nxt < 32) ? nxt : 0);
                pb0[j] = bp[tn * 128];
                pb1[j] = bp[tn * 128 + 64];
                pwc[j] = wp[tn * 16];
            }

#pragma unroll
            for (int g = 0; g < 4; ++g) {
                f32x4 acc;
                acc = __builtin_amdgcn_mfma_f32_16x16x32_bf16(afones, bc2, x2c[g], 0, 0, 0);
                acc = __builtin_amdgcn_mfma_f32_16x16x32_bf16(afrag[g][0], b0, acc, 0, 0, 0);
                acc = __builtin_amdgcn_mfma_f32_16x16x32_bf16(afrag[g][1], b1, acc, 0, 0, 0);
#pragma unroll
                for (int b = 0; b < 4; ++b) {
                    float d = __builtin_amdgcn_sqrtf(fabsf(acc[b]));
                    sum[g][b] = fmaf(w, d, sum[g][b]);
                }
            }
        }
    }

    // Reduce over the 16 col-lanes of this wave's half, park in LDS.
#pragma unroll
    for (int g = 0; g < 4; ++g) {
#pragma unroll
        for (int b = 0; b < 4; ++b) {
            float v = sum[g][b];
            v += __shfl_xor(v, 1, 64);
            v += __shfl_xor(v, 2, 64);
            v += __shfl_xor(v, 4, 64);
            v += __shfl_xor(v, 8, 64);
            if (lo == 0) part[wave][g * 16 + hi * 4 + b] = v;
        }
    }
    __syncthreads();

    // Combine the two center-halves and write 128 rows.
    const int tid = threadIdx.x;
    if (tid < 128) {
        const int p = tid >> 6;
        const int r = tid & 63;
        const float s = part[2 * p][r] + part[2 * p + 1][r];
        out[blockIdx.x * 128 + p * 64 + r] = madp[0] - s;
    }
}

extern "C" void kernel_launch(void* const* d_in, const int* in_sizes, int n_in,
                              void* d_out, int out_size, void* d_ws, size_t ws_size,
                              hipStream_t stream) {
    const float* x       = (const float*)d_in[0];
    const float* centers = (const float*)d_in[1];
    const float* coefs   = (const float*)d_in[2];
    const float* mad     = (const float*)d_in[3];
    float* out = (float*)d_out;

    float2* wc2  = (float2*)d_ws;
    short8* bfrag = (short8*)((char*)d_ws + NC * sizeof(float2));

    const int N = in_sizes[0] / DIM;

    coef_kernel<<<1, NC, 0, stream>>>(coefs, wc2);
    center_kernel<<<NC / 64, 64, 0, stream>>>(centers, wc2, bfrag);
    dist_kernel<<<N / 128, 256, 0, stream>>>(x, wc2, (const bf16x8*)bfrag, mad, out);
}